// Round 3
// baseline (279.967 us; speedup 1.0000x reference)
//
#include <hip/hip_runtime.h>
#include <hip/hip_bf16.h>

#define BB 2
#define CC 128
#define HH 48
#define WW 48
#define NN (HH*WW)          // 2304
#define PB 26               // 25 bins + spill (only ever gets +0.0)
#define HST 27              // private hist stride (odd -> bank spread)
#define QT 32               // queries per block (32x32 MFMA N-dim)
#define MT 128              // m per iteration (4 waves x 32)
#define MSPLIT 6            // m-range split -> 864 blocks
#define NTILES (NN/QT)      // 72
#define ITERS (NN/MSPLIT/MT)  // 3
#define SLICE (QT*PB)       // 832 floats per partial slice

typedef __bf16 bf16x8 __attribute__((ext_vector_type(8)));
typedef float  f32x16 __attribute__((ext_vector_type(16)));
typedef unsigned short u16;

static __device__ __forceinline__ u16 f2bf(float x) {
    __hip_bfloat16 h = __float2bfloat16(x);
    return __builtin_bit_cast(u16, h);
}

// Fused producer: blocks [0,144) transpose img1 -> Qt[b][n][c]; blocks
// [144,288) bilinear grid-sample img2 -> Dt[b][m][c]. Both write bf16x16
// channel chunks (two uint4 stores). Block 0 thread 0 zeroes d_out.
__global__ __launch_bounds__(256)
void k_prep(const float* __restrict__ img1, const float* __restrict__ img2,
            const float* __restrict__ grid, u16* __restrict__ Qt,
            u16* __restrict__ Dt, float* __restrict__ out) {
    int blk = blockIdx.x;
    if (blk == 0 && threadIdx.x == 0) out[0] = 0.0f;
    bool isg = blk >= 144;
    int bb  = isg ? blk - 144 : blk;
    int bm  = (bb >> 3) * 256 + threadIdx.x;   // b*NN + n, 18*256 = 4608
    int cc0 = (bb & 7) * 16;
    int b   = bm / NN;
    int p   = bm - b * NN;                     // n (or m)
    u16 tmp[16];
    if (!isg) {
        const float* im = img1 + (size_t)b * CC * NN + (size_t)cc0 * NN;
        #pragma unroll
        for (int c = 0; c < 16; ++c) tmp[c] = f2bf(im[(size_t)c * NN + p]);
        uint4* dst = reinterpret_cast<uint4*>(Qt + (size_t)bm * CC + cc0);
        dst[0] = *reinterpret_cast<uint4*>(&tmp[0]);
        dst[1] = *reinterpret_cast<uint4*>(&tmp[8]);
    } else {
        float gx = grid[bm * 2 + 0];
        float gy = grid[bm * 2 + 1];
        float ix = ((gx + 1.0f) * (float)WW - 1.0f) * 0.5f;
        float iy = ((gy + 1.0f) * (float)HH - 1.0f) * 0.5f;
        float x0f = floorf(ix), y0f = floorf(iy);
        float wx1 = ix - x0f, wy1 = iy - y0f;
        float wx0 = 1.0f - wx1, wy0 = 1.0f - wy1;
        int x0 = (int)x0f, y0 = (int)y0f;
        bool xv0 = (x0 >= 0) && (x0 < WW);
        bool xv1 = (x0 + 1 >= 0) && (x0 + 1 < WW);
        bool yv0 = (y0 >= 0) && (y0 < HH);
        bool yv1 = (y0 + 1 >= 0) && (y0 + 1 < HH);
        int x0c = min(max(x0, 0), WW - 1), x1c = min(max(x0 + 1, 0), WW - 1);
        int y0c = min(max(y0, 0), HH - 1), y1c = min(max(y0 + 1, 0), HH - 1);
        float w00 = (xv0 && yv0) ? wx0 * wy0 : 0.0f;
        float w01 = (xv1 && yv0) ? wx1 * wy0 : 0.0f;
        float w10 = (xv0 && yv1) ? wx0 * wy1 : 0.0f;
        float w11 = (xv1 && yv1) ? wx1 * wy1 : 0.0f;
        int p00 = y0c * WW + x0c, p01 = y0c * WW + x1c;
        int p10 = y1c * WW + x0c, p11 = y1c * WW + x1c;
        const float* im = img2 + (size_t)b * CC * NN + (size_t)cc0 * NN;
        #pragma unroll
        for (int c = 0; c < 16; ++c) {
            const float* pl = im + (size_t)c * NN;
            tmp[c] = f2bf(pl[p00] * w00 + pl[p01] * w01 + pl[p10] * w10 + pl[p11] * w11);
        }
        uint4* dst = reinterpret_cast<uint4*>(Dt + (size_t)bm * CC + cc0);
        dst[0] = *reinterpret_cast<uint4*>(&tmp[0]);
        dst[1] = *reinterpret_cast<uint4*>(&tmp[8]);
    }
}

// main: 32x32x16 MFMA, C[m][q] so each lane owns one query (q = lane&31).
// Per-(wave,query) LDS hists updated with ds_add_f32 (single DS op per bin,
// atomic-safe for the 2 lanes sharing a query). Partial hists plain-stored
// to global slices (no global atomics, no memset needed).
__global__ __launch_bounds__(256)
void k_main(const u16* __restrict__ Qt, const u16* __restrict__ Dt,
            float* __restrict__ Hall, float* __restrict__ Hpos) {
    __shared__ u16  Qs[QT * 136];        // 8704 B
    __shared__ u16  Ds[MT * 136];        // 34816 B
    __shared__ float priv[128 * HST];    // per (wave, query) hist: 13824 B
    __shared__ float posh[QT * PB];      // shared positives hist: 3328 B

    int tid  = threadIdx.x;
    int bidx = blockIdx.x;               // ((b*72 + ntile)*6 + ms)
    int b     = bidx / (NTILES * MSPLIT);
    int rem   = bidx % (NTILES * MSPLIT);
    int ntile = rem / MSPLIT;
    int ms    = rem % MSPLIT;
    int n0 = ntile * QT;

    for (int i = tid; i < 128 * HST; i += 256) priv[i] = 0.0f;
    for (int i = tid; i < QT * PB; i += 256) posh[i] = 0.0f;
    #pragma unroll
    for (int k2 = 0; k2 < 2; ++k2) {     // Q tile: 32 rows x 16 uint4
        int idx = tid + k2 * 256;
        int row = idx >> 4, col = idx & 15;
        *reinterpret_cast<uint4*>(&Qs[row * 136 + col * 8]) =
            *reinterpret_cast<const uint4*>(Qt + ((size_t)(b * NN + n0 + row)) * CC + col * 8);
    }
    int lane = tid & 63, wave = tid >> 6, h = lane >> 5, l31 = lane & 31;
    int q  = l31;
    int n  = n0 + q;
    int rn = n / WW, cn = n % WW;
    float* ph = &priv[(wave * 32 + l31) * HST];

    int mstart = ms * (NN / MSPLIT);
    for (int it = 0; it < ITERS; ++it) {
        int m0 = mstart + it * MT;
        __syncthreads();
        #pragma unroll
        for (int k2 = 0; k2 < 8; ++k2) { // D tile: 128 rows x 16 uint4
            int idx = tid + k2 * 256;
            int row = idx >> 4, col = idx & 15;
            *reinterpret_cast<uint4*>(&Ds[row * 136 + col * 8]) =
                *reinterpret_cast<const uint4*>(Dt + ((size_t)(b * NN + m0 + row)) * CC + col * 8);
        }
        __syncthreads();

        f32x16 acc = {0.f,0.f,0.f,0.f,0.f,0.f,0.f,0.f,0.f,0.f,0.f,0.f,0.f,0.f,0.f,0.f};
        #pragma unroll
        for (int kc = 0; kc < 8; ++kc) {  // K = 128 = 8 x 16
            // A[m][k]: m = l31 (+wave*32), k = h*8 + j ; B[q][k]: q = l31
            bf16x8 av = *reinterpret_cast<const bf16x8*>(&Ds[(wave * 32 + l31) * 136 + kc * 16 + h * 8]);
            bf16x8 bv = *reinterpret_cast<const bf16x8*>(&Qs[l31 * 136 + kc * 16 + h * 8]);
            acc = __builtin_amdgcn_mfma_f32_32x32x16_bf16(av, bv, acc, 0, 0, 0);
        }

        int mbase = m0 + wave * 32 + 4 * h;   // C: col=l31 (q), row=(r&3)+8*(r>>2)+4*h (m)
        #pragma unroll
        for (int r = 0; r < 16; ++r) {
            int mloc = (r & 3) + 8 * (r >> 2);
            float s  = acc[r];
            float t  = fminf(fmaxf(fmaf(-12.0f, s, 12.0f), 0.0f), 24.0f);
            float cf = floorf(t);
            float f  = t - cf;
            int   c0 = (int)cf;               // [0,24]; c0==24 -> f==0 -> spill +0
            atomicAdd(&ph[c0],     1.0f - f); // ds_add_f32, no return
            atomicAdd(&ph[c0 + 1], f);
            int m  = mbase + mloc;
            int rm = m / WW, cm = m - rm * WW;
            int dr = rn - rm, dc = cn - cm;
            if ((unsigned)(dr + 4) <= 8u && (unsigned)(dc + 4) <= 8u) {
                atomicAdd(&posh[q * PB + c0],     1.0f - f);
                atomicAdd(&posh[q * PB + c0 + 1], f);
            }
        }
    }
    __syncthreads();
    // flush partial slices, [c][q] layout (coalesced store AND finalize load)
    float* oa = Hall + (size_t)bidx * SLICE;
    float* op = Hpos + (size_t)bidx * SLICE;
    for (int idx = tid; idx < SLICE; idx += 256) {
        int c = idx >> 5, qq = idx & 31;
        float s2 = priv[qq * HST + c] + priv[(32 + qq) * HST + c]
                 + priv[(64 + qq) * HST + c] + priv[(96 + qq) * HST + c];
        oa[idx] = s2;
        op[idx] = posh[qq * PB + c];
    }
}

// AP from MSPLIT partial hists + reliability + mean -> scalar
__global__ __launch_bounds__(256)
void k_finalize(const float* __restrict__ Hall, const float* __restrict__ Hpos,
                const float* __restrict__ rel, float* __restrict__ out) {
    int gid = blockIdx.x * 256 + threadIdx.x;   // 0..4607
    int b = gid / NN, nloc = gid % NN;
    int ntile = nloc >> 5, qq = nloc & 31;
    size_t base = ((size_t)(b * NTILES + ntile) * MSPLIT) * SLICE + qq;
    const float* ha = Hall + base;
    const float* hp = Hpos + base;
    float cumr = 0.f, cumn = 0.f, apn = 0.f, totr = 0.f;
    #pragma unroll
    for (int c = 0; c < 25; ++c) {
        float a = 0.f, r = 0.f;
        #pragma unroll
        for (int s = 0; s < MSPLIT; ++s) {
            a += ha[(size_t)s * SLICE + c * 32];
            r += hp[(size_t)s * SLICE + c * 32];
        }
        cumr += r; cumn += a;
        apn  += (cumr / (1e-16f + cumn)) * r;
        totr += r;
    }
    float ap = apn / totr;                      // totr >= 25 (self-neighborhood)
    float rl = rel[gid];
    float loss = 1.0f - (ap * rl + 0.5f * (1.0f - rl));

    for (int off = 32; off > 0; off >>= 1) loss += __shfl_down(loss, off, 64);
    __shared__ float wsum[4];
    int ln = threadIdx.x & 63, wv = threadIdx.x >> 6;
    if (ln == 0) wsum[wv] = loss;
    __syncthreads();
    if (threadIdx.x == 0) {
        float t = wsum[0] + wsum[1] + wsum[2] + wsum[3];
        atomicAdd(out, t * (1.0f / (float)(BB * NN)));
    }
}

extern "C" void kernel_launch(void* const* d_in, const int* in_sizes, int n_in,
                              void* d_out, int out_size, void* d_ws, size_t ws_size,
                              hipStream_t stream) {
    const float* img1 = (const float*)d_in[0];
    const float* img2 = (const float*)d_in[1];
    const float* rel  = (const float*)d_in[2];
    const float* grid = (const float*)d_in[3];

    char* ws = (char*)d_ws;
    const size_t qt_bytes   = (size_t)BB * NN * CC * sizeof(u16);              // 1.18 MB
    const size_t part_bytes = (size_t)BB * NTILES * MSPLIT * SLICE * sizeof(float);  // 2.88 MB
    u16*   Qt   = (u16*)ws;
    u16*   Dt   = (u16*)(ws + qt_bytes);
    float* Hall = (float*)(ws + 2 * qt_bytes);
    float* Hpos = (float*)(ws + 2 * qt_bytes + part_bytes);

    k_prep    <<<288, 256, 0, stream>>>(img1, img2, grid, Qt, Dt, (float*)d_out);
    k_main    <<<BB * NTILES * MSPLIT, 256, 0, stream>>>(Qt, Dt, Hall, Hpos);
    k_finalize<<<(BB * NN) / 256, 256, 0, stream>>>(Hall, Hpos, rel, (float*)d_out);
}

// Round 4
// 98.802 us; speedup vs baseline: 2.8336x; 2.8336x over previous
//
#include <hip/hip_runtime.h>
#include <hip/hip_bf16.h>

#define BB 2
#define CC 128
#define HH 48
#define WW 48
#define NN (HH*WW)          // 2304
#define PB 26               // 25 bins + spill (only ever gets +0.0)
#define HST 27              // private hist stride (odd -> bank spread)
#define QT 16               // queries per block
#define MT 64               // m per iteration
#define MSPLIT 4            // m-range split -> 1152 blocks
#define NTILES (NN/QT)      // 144
#define ITERS (NN/MSPLIT/MT)  // 9
#define SLICE (QT*PB)       // 416 floats per partial slice
#define PSCALE 65536.0f
#define PINV   (1.0f/65536.0f)

typedef __bf16 bf16x8 __attribute__((ext_vector_type(8)));
typedef float  f32x4  __attribute__((ext_vector_type(4)));
typedef unsigned short u16;
typedef unsigned int   u32;

static __device__ __forceinline__ u16 f2bf(float x) {
    __hip_bfloat16 h = __float2bfloat16(x);
    return __builtin_bit_cast(u16, h);
}

// Fused producer: blocks [0,144) transpose img1 -> Qt[b][n][c]; blocks
// [144,288) bilinear grid-sample img2 -> Dt[b][m][c]. Block 0 zeroes d_out.
__global__ __launch_bounds__(256)
void k_prep(const float* __restrict__ img1, const float* __restrict__ img2,
            const float* __restrict__ grid, u16* __restrict__ Qt,
            u16* __restrict__ Dt, float* __restrict__ out) {
    int blk = blockIdx.x;
    if (blk == 0 && threadIdx.x == 0) out[0] = 0.0f;
    bool isg = blk >= 144;
    int bb  = isg ? blk - 144 : blk;
    int bm  = (bb >> 3) * 256 + threadIdx.x;   // b*NN + n, 18*256 = 4608
    int cc0 = (bb & 7) * 16;
    int b   = bm / NN;
    int p   = bm - b * NN;
    u16 tmp[16];
    if (!isg) {
        const float* im = img1 + (size_t)b * CC * NN + (size_t)cc0 * NN;
        #pragma unroll
        for (int c = 0; c < 16; ++c) tmp[c] = f2bf(im[(size_t)c * NN + p]);
        uint4* dst = reinterpret_cast<uint4*>(Qt + (size_t)bm * CC + cc0);
        dst[0] = *reinterpret_cast<uint4*>(&tmp[0]);
        dst[1] = *reinterpret_cast<uint4*>(&tmp[8]);
    } else {
        float gx = grid[bm * 2 + 0];
        float gy = grid[bm * 2 + 1];
        float ix = ((gx + 1.0f) * (float)WW - 1.0f) * 0.5f;
        float iy = ((gy + 1.0f) * (float)HH - 1.0f) * 0.5f;
        float x0f = floorf(ix), y0f = floorf(iy);
        float wx1 = ix - x0f, wy1 = iy - y0f;
        float wx0 = 1.0f - wx1, wy0 = 1.0f - wy1;
        int x0 = (int)x0f, y0 = (int)y0f;
        bool xv0 = (x0 >= 0) && (x0 < WW);
        bool xv1 = (x0 + 1 >= 0) && (x0 + 1 < WW);
        bool yv0 = (y0 >= 0) && (y0 < HH);
        bool yv1 = (y0 + 1 >= 0) && (y0 + 1 < HH);
        int x0c = min(max(x0, 0), WW - 1), x1c = min(max(x0 + 1, 0), WW - 1);
        int y0c = min(max(y0, 0), HH - 1), y1c = min(max(y0 + 1, 0), HH - 1);
        float w00 = (xv0 && yv0) ? wx0 * wy0 : 0.0f;
        float w01 = (xv1 && yv0) ? wx1 * wy0 : 0.0f;
        float w10 = (xv0 && yv1) ? wx0 * wy1 : 0.0f;
        float w11 = (xv1 && yv1) ? wx1 * wy1 : 0.0f;
        int p00 = y0c * WW + x0c, p01 = y0c * WW + x1c;
        int p10 = y1c * WW + x0c, p11 = y1c * WW + x1c;
        const float* im = img2 + (size_t)b * CC * NN + (size_t)cc0 * NN;
        #pragma unroll
        for (int c = 0; c < 16; ++c) {
            const float* pl = im + (size_t)c * NN;
            tmp[c] = f2bf(pl[p00] * w00 + pl[p01] * w01 + pl[p10] * w10 + pl[p11] * w11);
        }
        uint4* dst = reinterpret_cast<uint4*>(Dt + (size_t)bm * CC + cc0);
        dst[0] = *reinterpret_cast<uint4*>(&tmp[0]);
        dst[1] = *reinterpret_cast<uint4*>(&tmp[8]);
    }
}

// main: 16x16x32 MFMA (C[m][q], q = lane&15). Per-THREAD private LDS hist,
// plain ld/add/st RMW (NO float atomics -> no CAS-loop lowering). Positives
// via u32 fixed-point LDS atomics (native single instruction, rare hits).
// Partial hists plain-stored to per-block global slices.
__global__ __launch_bounds__(256)
void k_main(const u16* __restrict__ Qt, const u16* __restrict__ Dt,
            float* __restrict__ Hall, float* __restrict__ Hpos) {
    __shared__ u16  Qs[QT * 136];       //  4352 B
    __shared__ u16  Ds[MT * 136];       // 17408 B
    __shared__ float priv[256 * HST];   // 27648 B  per-thread hist
    __shared__ u32   poshu[QT * PB];    //  1664 B  positives (u32 fixed-point)

    int tid  = threadIdx.x;
    int bidx = blockIdx.x;              // ((b*144 + ntile)*4 + ms)
    int b     = bidx / (NTILES * MSPLIT);
    int rem   = bidx % (NTILES * MSPLIT);
    int ntile = rem / MSPLIT;
    int ms    = rem % MSPLIT;
    int n0 = ntile * QT;

    for (int i = tid; i < 256 * HST; i += 256) priv[i] = 0.0f;
    for (int i = tid; i < QT * PB; i += 256) poshu[i] = 0u;
    {   // Q tile: 16 rows x 16 uint4
        int row = tid >> 4, col = tid & 15;
        *reinterpret_cast<uint4*>(&Qs[row * 136 + col * 8]) =
            *reinterpret_cast<const uint4*>(Qt + ((size_t)(b * NN + n0 + row)) * CC + col * 8);
    }
    int lane = tid & 63, wave = tid >> 6, quad = lane >> 4, l15 = lane & 15;
    int q  = l15;                       // this lane's query, whole kernel
    int n  = n0 + q;
    int rn = n / WW, cn = n % WW;
    float* ph = &priv[tid * HST];

    int mstart = ms * (NN / MSPLIT);
    for (int it = 0; it < ITERS; ++it) {
        int m0 = mstart + it * MT;
        __syncthreads();
        #pragma unroll
        for (int k = 0; k < 4; ++k) {   // D tile: 64 rows x 16 uint4
            int idx = tid + k * 256;
            int row = idx >> 4, col = idx & 15;
            *reinterpret_cast<uint4*>(&Ds[row * 136 + col * 8]) =
                *reinterpret_cast<const uint4*>(Dt + ((size_t)(b * NN + m0 + row)) * CC + col * 8);
        }
        __syncthreads();

        f32x4 acc = {0.f, 0.f, 0.f, 0.f};
        #pragma unroll
        for (int kc = 0; kc < 4; ++kc) {
            // A = D rows (M dim = m), B = Q rows (N dim = q) -> C[m][q]
            bf16x8 av = *reinterpret_cast<const bf16x8*>(&Ds[(wave * 16 + l15) * 136 + kc * 32 + quad * 8]);
            bf16x8 bv = *reinterpret_cast<const bf16x8*>(&Qs[l15 * 136 + kc * 32 + quad * 8]);
            acc = __builtin_amdgcn_mfma_f32_16x16x32_bf16(av, bv, acc, 0, 0, 0);
        }

        int mb = m0 + wave * 16 + quad * 4;   // C row = quad*4+i (m), col = l15 (q)
        #pragma unroll
        for (int i = 0; i < 4; ++i) {
            float s  = acc[i];
            float t  = fminf(fmaxf(fmaf(-12.0f, s, 12.0f), 0.0f), 24.0f);
            float cf = floorf(t);
            float f  = t - cf;
            int   c0 = (int)cf;               // [0,24]; c0==24 -> f==0 -> spill +0
            float h0 = ph[c0], h1 = ph[c0 + 1];
            ph[c0]     = h0 + (1.0f - f);     // plain ds RMW, private -> race-free
            ph[c0 + 1] = h1 + f;
            int m  = mb + i;
            int rm = m / WW, cm = m - rm * WW;
            int dr = rn - rm, dc = cn - cm;
            if ((unsigned)(dr + 4) <= 8u && (unsigned)(dc + 4) <= 8u) {
                u32 w0 = (u32)(fmaf(-PSCALE, f, PSCALE) + 0.5f);  // (1-f)*2^16
                u32 w1 = (u32)(f * PSCALE + 0.5f);
                atomicAdd(&poshu[q * PB + c0],     w0);   // native u32 LDS atomic
                atomicAdd(&poshu[q * PB + c0 + 1], w1);
            }
        }
    }
    __syncthreads();
    // flush partial slices, [c][q] layout (coalesced both sides)
    float* oa = Hall + (size_t)bidx * SLICE;
    float* op = Hpos + (size_t)bidx * SLICE;
    for (int idx = tid; idx < SLICE; idx += 256) {
        int c = idx >> 4, qq = idx & 15;
        float s2 = 0.0f;
        #pragma unroll
        for (int j = 0; j < 16; ++j) s2 += priv[(j * 16 + qq) * HST + c];
        oa[idx] = s2;
        op[idx] = (float)poshu[qq * PB + c] * PINV;
    }
}

// AP from MSPLIT partial hists + reliability + mean -> scalar
__global__ __launch_bounds__(256)
void k_finalize(const float* __restrict__ Hall, const float* __restrict__ Hpos,
                const float* __restrict__ rel, float* __restrict__ out) {
    int gid = blockIdx.x * 256 + threadIdx.x;   // 0..4607
    int b = gid / NN, nloc = gid % NN;
    int ntile = nloc >> 4, qq = nloc & 15;
    size_t base = ((size_t)(b * NTILES + ntile) * MSPLIT) * SLICE + qq;
    const float* ha = Hall + base;
    const float* hp = Hpos + base;
    float cumr = 0.f, cumn = 0.f, apn = 0.f, totr = 0.f;
    #pragma unroll
    for (int c = 0; c < 25; ++c) {
        float a = 0.f, r = 0.f;
        #pragma unroll
        for (int s = 0; s < MSPLIT; ++s) {
            a += ha[(size_t)s * SLICE + c * 16];
            r += hp[(size_t)s * SLICE + c * 16];
        }
        cumr += r; cumn += a;
        apn  += (cumr / (1e-16f + cumn)) * r;
        totr += r;
    }
    float ap = apn / totr;                      // totr >= 1 (self-match)
    float rl = rel[gid];
    float loss = 1.0f - (ap * rl + 0.5f * (1.0f - rl));

    for (int off = 32; off > 0; off >>= 1) loss += __shfl_down(loss, off, 64);
    __shared__ float wsum[4];
    int ln = threadIdx.x & 63, wv = threadIdx.x >> 6;
    if (ln == 0) wsum[wv] = loss;
    __syncthreads();
    if (threadIdx.x == 0) {
        float t = wsum[0] + wsum[1] + wsum[2] + wsum[3];
        atomicAdd(out, t * (1.0f / (float)(BB * NN)));
    }
}

extern "C" void kernel_launch(void* const* d_in, const int* in_sizes, int n_in,
                              void* d_out, int out_size, void* d_ws, size_t ws_size,
                              hipStream_t stream) {
    const float* img1 = (const float*)d_in[0];
    const float* img2 = (const float*)d_in[1];
    const float* rel  = (const float*)d_in[2];
    const float* grid = (const float*)d_in[3];

    char* ws = (char*)d_ws;
    const size_t qt_bytes   = (size_t)BB * NN * CC * sizeof(u16);                    // 1.18 MB
    const size_t part_bytes = (size_t)BB * NTILES * MSPLIT * SLICE * sizeof(float);  // 1.92 MB
    u16*   Qt   = (u16*)ws;
    u16*   Dt   = (u16*)(ws + qt_bytes);
    float* Hall = (float*)(ws + 2 * qt_bytes);
    float* Hpos = (float*)(ws + 2 * qt_bytes + part_bytes);

    k_prep    <<<288, 256, 0, stream>>>(img1, img2, grid, Qt, Dt, (float*)d_out);
    k_main    <<<BB * NTILES * MSPLIT, 256, 0, stream>>>(Qt, Dt, Hall, Hpos);
    k_finalize<<<(BB * NN) / 256, 256, 0, stream>>>(Hall, Hpos, rel, (float*)d_out);
}